// Round 1
// baseline (1590.541 us; speedup 1.0000x reference)
//
#include <hip/hip_runtime.h>
#include <hip/hip_bf16.h>
#include <math.h>

typedef __bf16 bf16;
typedef bf16 bf16x8 __attribute__((ext_vector_type(8)));
typedef float f32x4 __attribute__((ext_vector_type(4)));

#define BLROWS 4096   // B*L
#define HD 1024
#define DIN 2048
#define NST 16
#define RNK 128
#define LSEQ 2048

// ---------------- helpers ----------------
__device__ __forceinline__ void gload_lds16(const void* g, void* l) {
  __builtin_amdgcn_global_load_lds(
      (const __attribute__((address_space(1))) unsigned int*)g,
      (__attribute__((address_space(3))) unsigned int*)l, 16, 0, 0);
}

__device__ __forceinline__ float silu_f(float x) {
  return x / (1.f + expf(-x));
}

// ---------------- f32 -> bf16 convert ----------------
__global__ __launch_bounds__(256) void cvt_bf16_kernel(const float* __restrict__ src,
                                                       bf16* __restrict__ dst, int n4) {
  int i = blockIdx.x * 256 + threadIdx.x;
  if (i >= n4) return;
  f32x4 v = *(const f32x4*)(src + (size_t)i * 4);
  bf16* o = dst + (size_t)i * 4;
  o[0] = (bf16)v.x; o[1] = (bf16)v.y; o[2] = (bf16)v.z; o[3] = (bf16)v.w;
}

// ---------------- RMSNorm -> bf16 ----------------
__global__ __launch_bounds__(256) void rmsnorm_kernel(const float* __restrict__ x,
                                                      const float* __restrict__ w,
                                                      bf16* __restrict__ xn) {
  int row = blockIdx.x;
  int t = threadIdx.x;
  const float* xr = x + (size_t)row * HD;
  f32x4 v = *(const f32x4*)(xr + t * 4);
  float s = v.x * v.x + v.y * v.y + v.z * v.z + v.w * v.w;
#pragma unroll
  for (int m = 1; m < 64; m <<= 1) s += __shfl_xor(s, m, 64);
  __shared__ float red[4];
  if ((t & 63) == 0) red[t >> 6] = s;
  __syncthreads();
  float tot = red[0] + red[1] + red[2] + red[3];
  float sc = rsqrtf(tot * (1.f / HD) + 1e-6f);
  const float* wr = w + t * 4;
  bf16* o = xn + (size_t)row * HD + t * 4;
  o[0] = (bf16)(v.x * sc * wr[0]);
  o[1] = (bf16)(v.y * sc * wr[1]);
  o[2] = (bf16)(v.z * sc * wr[2]);
  o[3] = (bf16)(v.w * sc * wr[3]);
}

// ---------------- GEMM: C[M,N] = A[M,K] * B[N,K]^T (+ epilogue) ----------------
// BM=BN=128, BK=64, 256 threads (4 waves 2x2), mfma_f32_16x16x32_bf16
enum { EPI_NONE = 0, EPI_SOFTPLUS = 1, EPI_RESID = 2 };

template <int EPI>
__global__ __launch_bounds__(256, 2) void gemm_bt(const bf16* __restrict__ A,
                                                  const bf16* __restrict__ B,
                                                  float* __restrict__ C,
                                                  const float* __restrict__ bias,
                                                  const float* __restrict__ resid,
                                                  int M, int N, int K, int ldc) {
  __shared__ __align__(16) bf16 lA[128 * 64];
  __shared__ __align__(16) bf16 lB[128 * 64];
  const int tid = threadIdx.x;
  const int wave = tid >> 6;
  const int lane = tid & 63;
  const int m0 = blockIdx.y * 128;
  const int n0 = blockIdx.x * 128;
  const int wr = wave >> 1, wc = wave & 1;
  f32x4 acc[4][4] = {};
  const int lrow = lane >> 3;          // 0..7
  const int lcole = (lane & 7) * 8;    // element offset 0..56

  for (int k0 = 0; k0 < K; k0 += 64) {
#pragma unroll
    for (int j = 0; j < 4; ++j) {
      int chunk = wave * 4 + j;
      int row = chunk * 8 + lrow;
      gload_lds16(A + (size_t)(m0 + row) * K + k0 + lcole, lA + chunk * 8 * 64);
      gload_lds16(B + (size_t)(n0 + row) * K + k0 + lcole, lB + chunk * 8 * 64);
    }
    __syncthreads();  // compiler drains vmcnt before barrier -> LDS valid
#pragma unroll
    for (int kk = 0; kk < 64; kk += 32) {
      bf16x8 af[4], bfr[4];
      const int kof = kk + ((lane >> 4) * 8);
#pragma unroll
      for (int i = 0; i < 4; ++i)
        af[i] = *(const bf16x8*)&lA[(wr * 64 + i * 16 + (lane & 15)) * 64 + kof];
#pragma unroll
      for (int j = 0; j < 4; ++j)
        bfr[j] = *(const bf16x8*)&lB[(wc * 64 + j * 16 + (lane & 15)) * 64 + kof];
#pragma unroll
      for (int i = 0; i < 4; ++i)
#pragma unroll
        for (int j = 0; j < 4; ++j)
          acc[i][j] = __builtin_amdgcn_mfma_f32_16x16x32_bf16(af[i], bfr[j], acc[i][j], 0, 0, 0);
    }
    __syncthreads();
  }

  const int crow0 = (lane >> 4) * 4;
  const int ccol = lane & 15;
#pragma unroll
  for (int i = 0; i < 4; ++i) {
#pragma unroll
    for (int j = 0; j < 4; ++j) {
      int col = n0 + wc * 64 + j * 16 + ccol;
      if (col >= N) continue;
#pragma unroll
      for (int v = 0; v < 4; ++v) {
        int row = m0 + wr * 64 + i * 16 + crow0 + v;
        float val = acc[i][j][v];
        if (EPI == EPI_SOFTPLUS) {
          val += bias[col];
          val = (val > 20.f) ? val : log1pf(expf(val));
        } else if (EPI == EPI_RESID) {
          val += resid[(size_t)row * ldc + col];
        }
        C[(size_t)row * ldc + col] = val;
      }
    }
  }
}

// ---------------- causal depthwise conv K=4 + SiLU ----------------
__global__ __launch_bounds__(256) void conv_silu_kernel(const float* __restrict__ xz,
                                                        const float* __restrict__ cw,
                                                        const float* __restrict__ cb,
                                                        float* __restrict__ xcf,
                                                        bf16* __restrict__ xcb) {
  int idx = blockIdx.x * 256 + threadIdx.x;  // over B*L*DIN = 8388608
  int d = idx & (DIN - 1);
  int bl = idx >> 11;
  int l = bl & (LSEQ - 1);
  float acc = cb[d];
  const float* base = xz + (size_t)bl * 4096 + d;
#pragma unroll
  for (int k = 0; k < 4; ++k) {
    int ll = l - 3 + k;
    if (ll >= 0) acc += base[(ptrdiff_t)(k - 3) * 4096] * cw[d * 4 + k];
  }
  float sv = silu_f(acc);
  xcf[idx] = sv;
  xcb[idx] = (bf16)sv;
}

// ---------------- extract dt_x cols [0,128) -> bf16 ----------------
__global__ __launch_bounds__(256) void extract_dtx_kernel(const float* __restrict__ xdbl,
                                                          bf16* __restrict__ dtx) {
  int i = blockIdx.x * 256 + threadIdx.x;  // 4096*128
  int r = i >> 7, c = i & 127;
  dtx[i] = (bf16)xdbl[(size_t)r * 160 + c];
}

// ---------------- selective scan ----------------
// 16 lanes per (b,d) group; 4096 groups; sequential over L with prefetch.
__global__ __launch_bounds__(256) void scan_kernel(const float* __restrict__ xdbl,
                                                   const float* __restrict__ dt,
                                                   const float* __restrict__ xc,
                                                   const float* __restrict__ xz,
                                                   const float* __restrict__ A_log,
                                                   const float* __restrict__ Dp,
                                                   bf16* __restrict__ y) {
  int tid = blockIdx.x * 256 + threadIdx.x;
  int n = tid & 15;
  int g = tid >> 4;  // b*2048 + d
  int d = g & (DIN - 1);
  int b = g >> 11;
  float Acoef = -expf(A_log[d * NST + n]);
  float Dv = Dp[d];
  const float* dtp = dt + (size_t)b * LSEQ * DIN + d;
  const float* xp = xc + (size_t)b * LSEQ * DIN + d;
  const float* zp = xz + (size_t)b * LSEQ * 4096 + DIN + d;
  const float* xdp = xdbl + (size_t)b * LSEQ * 160;
  bf16* yp = y + (size_t)b * LSEQ * DIN + d;

  float h = 0.f;
  float dtv = dtp[0];
  float xv = xp[0];
  float Bv = xdp[128 + n];
  float Cv = xdp[144 + n];
  for (int l = 0; l < LSEQ; ++l) {
    float ndt = 0.f, nx = 0.f, nB = 0.f, nC = 0.f;
    if (l < LSEQ - 1) {
      ndt = dtp[(size_t)(l + 1) * DIN];
      nx = xp[(size_t)(l + 1) * DIN];
      nB = xdp[(size_t)(l + 1) * 160 + 128 + n];
      nC = xdp[(size_t)(l + 1) * 160 + 144 + n];
    }
    float dA = expf(dtv * Acoef);
    h = dA * h + (dtv * xv) * Bv;
    float yv = h * Cv;
    yv += __shfl_xor(yv, 1, 64);
    yv += __shfl_xor(yv, 2, 64);
    yv += __shfl_xor(yv, 4, 64);
    yv += __shfl_xor(yv, 8, 64);
    if (n == 0) {
      float zv = zp[(size_t)l * 4096];
      float outv = (yv + Dv * xv) * silu_f(zv);
      yp[(size_t)l * DIN] = (bf16)outv;
    }
    dtv = ndt; xv = nx; Bv = nB; Cv = nC;
  }
}

// ---------------- launch ----------------
extern "C" void kernel_launch(void* const* d_in, const int* in_sizes, int n_in,
                              void* d_out, int out_size, void* d_ws, size_t ws_size,
                              hipStream_t stream) {
  const float* x = (const float*)d_in[0];          // [2,2048,1024]
  const float* norm_w = (const float*)d_in[1];     // [1024]
  const float* in_proj_w = (const float*)d_in[2];  // [4096,1024]
  const float* conv_w = (const float*)d_in[3];     // [2048,1,4]
  const float* conv_b = (const float*)d_in[4];     // [2048]
  const float* x_proj_w = (const float*)d_in[5];   // [160,2048]
  const float* dt_proj_w = (const float*)d_in[6];  // [2048,128]
  const float* dt_proj_b = (const float*)d_in[7];  // [2048]
  const float* A_log = (const float*)d_in[8];      // [2048,16]
  const float* D_param = (const float*)d_in[9];    // [2048]
  const float* out_proj_w = (const float*)d_in[10];// [1024,2048]
  float* out = (float*)d_out;                      // [2,2048,1024]

  size_t off = 0;
  char* wsb = (char*)d_ws;
  auto alloc = [&](size_t bytes) {
    void* p = wsb + off;
    off += (bytes + 255) & ~(size_t)255;
    return p;
  };
  bf16* xn = (bf16*)alloc((size_t)BLROWS * HD * 2);
  bf16* w_in = (bf16*)alloc((size_t)4096 * HD * 2);
  float* xz = (float*)alloc((size_t)BLROWS * 4096 * 4);
  float* xcf = (float*)alloc((size_t)BLROWS * DIN * 4);
  bf16* xcb = (bf16*)alloc((size_t)BLROWS * DIN * 2);
  bf16* xpw = (bf16*)alloc((size_t)256 * DIN * 2);  // padded 160->256 rows
  float* xdbl = (float*)alloc((size_t)BLROWS * 160 * 4);
  bf16* dtx = (bf16*)alloc((size_t)BLROWS * RNK * 2);
  bf16* dtw = (bf16*)alloc((size_t)DIN * RNK * 2);
  float* dtf = (float*)alloc((size_t)BLROWS * DIN * 4);
  bf16* yb = (bf16*)alloc((size_t)BLROWS * DIN * 2);
  bf16* outw = (bf16*)alloc((size_t)HD * DIN * 2);
  (void)ws_size; (void)n_in; (void)in_sizes; (void)out_size;

  // convert weights to bf16
  cvt_bf16_kernel<<<(4096 * HD / 4 + 255) / 256, 256, 0, stream>>>(in_proj_w, w_in, 4096 * HD / 4);
  cvt_bf16_kernel<<<(160 * DIN / 4 + 255) / 256, 256, 0, stream>>>(x_proj_w, xpw, 160 * DIN / 4);
  cvt_bf16_kernel<<<(DIN * RNK / 4 + 255) / 256, 256, 0, stream>>>(dt_proj_w, dtw, DIN * RNK / 4);
  cvt_bf16_kernel<<<(HD * DIN / 4 + 255) / 256, 256, 0, stream>>>(out_proj_w, outw, HD * DIN / 4);

  // rmsnorm
  rmsnorm_kernel<<<BLROWS, 256, 0, stream>>>(x, norm_w, xn);

  // xz = xn @ in_proj_w^T : M=4096 N=4096 K=1024
  gemm_bt<EPI_NONE><<<dim3(32, 32), 256, 0, stream>>>(xn, w_in, xz, nullptr, nullptr,
                                                      BLROWS, 4096, HD, 4096);

  // conv + silu
  conv_silu_kernel<<<(BLROWS * DIN) / 256, 256, 0, stream>>>(xz, conv_w, conv_b, xcf, xcb);

  // x_dbl = xc @ x_proj_w^T : M=4096 N=160 K=2048
  gemm_bt<EPI_NONE><<<dim3(2, 32), 256, 0, stream>>>(xcb, xpw, xdbl, nullptr, nullptr,
                                                     BLROWS, 160, DIN, 160);

  // dt_x -> bf16
  extract_dtx_kernel<<<(BLROWS * RNK) / 256, 256, 0, stream>>>(xdbl, dtx);

  // dt = softplus(dt_x @ dt_proj_w^T + b) : M=4096 N=2048 K=128
  gemm_bt<EPI_SOFTPLUS><<<dim3(16, 32), 256, 0, stream>>>(dtx, dtw, dtf, dt_proj_b, nullptr,
                                                          BLROWS, DIN, RNK, DIN);

  // selective scan + silu(z) gate -> y bf16
  scan_kernel<<<(BLROWS * NST) / 256, 256, 0, stream>>>(xdbl, dtf, xcf, xz, A_log, D_param, yb);

  // out = y @ out_proj_w^T + residual : M=4096 N=1024 K=2048
  gemm_bt<EPI_RESID><<<dim3(8, 32), 256, 0, stream>>>(yb, outw, out, nullptr, x,
                                                      BLROWS, HD, DIN, HD);
}

// Round 2
// 439.530 us; speedup vs baseline: 3.6187x; 3.6187x over previous
//
#include <hip/hip_runtime.h>
#include <hip/hip_bf16.h>
#include <math.h>

typedef __bf16 bf16;
typedef bf16 bf16x8 __attribute__((ext_vector_type(8)));
typedef float f32x4 __attribute__((ext_vector_type(4)));

#define BLROWS 4096   // B*L
#define HD 1024
#define DIN 2048
#define NST 16
#define RNK 128
#define LSEQ 2048
#define NC 64         // chunks along L
#define LC 32         // L per chunk  (NC*LC == LSEQ)

// ---------------- helpers ----------------
__device__ __forceinline__ void gload_lds16(const void* g, void* l) {
  __builtin_amdgcn_global_load_lds(
      (const __attribute__((address_space(1))) unsigned int*)g,
      (__attribute__((address_space(3))) unsigned int*)l, 16, 0, 0);
}

__device__ __forceinline__ float silu_f(float x) {
  return x / (1.f + __expf(-x));
}

// ---------------- f32 -> bf16 convert ----------------
__global__ __launch_bounds__(256) void cvt_bf16_kernel(const float* __restrict__ src,
                                                       bf16* __restrict__ dst, int n4) {
  int i = blockIdx.x * 256 + threadIdx.x;
  if (i >= n4) return;
  f32x4 v = *(const f32x4*)(src + (size_t)i * 4);
  bf16* o = dst + (size_t)i * 4;
  o[0] = (bf16)v.x; o[1] = (bf16)v.y; o[2] = (bf16)v.z; o[3] = (bf16)v.w;
}

// ---------------- RMSNorm -> bf16 ----------------
__global__ __launch_bounds__(256) void rmsnorm_kernel(const float* __restrict__ x,
                                                      const float* __restrict__ w,
                                                      bf16* __restrict__ xn) {
  int row = blockIdx.x;
  int t = threadIdx.x;
  const float* xr = x + (size_t)row * HD;
  f32x4 v = *(const f32x4*)(xr + t * 4);
  float s = v.x * v.x + v.y * v.y + v.z * v.z + v.w * v.w;
#pragma unroll
  for (int m = 1; m < 64; m <<= 1) s += __shfl_xor(s, m, 64);
  __shared__ float red[4];
  if ((t & 63) == 0) red[t >> 6] = s;
  __syncthreads();
  float tot = red[0] + red[1] + red[2] + red[3];
  float sc = rsqrtf(tot * (1.f / HD) + 1e-6f);
  const float* wr = w + t * 4;
  bf16* o = xn + (size_t)row * HD + t * 4;
  o[0] = (bf16)(v.x * sc * wr[0]);
  o[1] = (bf16)(v.y * sc * wr[1]);
  o[2] = (bf16)(v.z * sc * wr[2]);
  o[3] = (bf16)(v.w * sc * wr[3]);
}

// ---------------- GEMM: C[M,N] = A[M,K] * B[N,K]^T (+ epilogue) ----------------
enum { EPI_NONE = 0, EPI_SOFTPLUS = 1, EPI_RESID = 2 };

template <int EPI>
__global__ __launch_bounds__(256, 2) void gemm_bt(const bf16* __restrict__ A,
                                                  const bf16* __restrict__ B,
                                                  float* __restrict__ C,
                                                  const float* __restrict__ bias,
                                                  const float* __restrict__ resid,
                                                  int M, int N, int K, int ldc) {
  __shared__ __align__(16) bf16 lA[128 * 64];
  __shared__ __align__(16) bf16 lB[128 * 64];
  const int tid = threadIdx.x;
  const int wave = tid >> 6;
  const int lane = tid & 63;
  const int m0 = blockIdx.y * 128;
  const int n0 = blockIdx.x * 128;
  const int wr = wave >> 1, wc = wave & 1;
  f32x4 acc[4][4] = {};
  const int lrow = lane >> 3;          // 0..7
  const int lcole = (lane & 7) * 8;    // element offset 0..56

  for (int k0 = 0; k0 < K; k0 += 64) {
#pragma unroll
    for (int j = 0; j < 4; ++j) {
      int chunk = wave * 4 + j;
      int row = chunk * 8 + lrow;
      gload_lds16(A + (size_t)(m0 + row) * K + k0 + lcole, lA + chunk * 8 * 64);
      gload_lds16(B + (size_t)(n0 + row) * K + k0 + lcole, lB + chunk * 8 * 64);
    }
    __syncthreads();
#pragma unroll
    for (int kk = 0; kk < 64; kk += 32) {
      bf16x8 af[4], bfr[4];
      const int kof = kk + ((lane >> 4) * 8);
#pragma unroll
      for (int i = 0; i < 4; ++i)
        af[i] = *(const bf16x8*)&lA[(wr * 64 + i * 16 + (lane & 15)) * 64 + kof];
#pragma unroll
      for (int j = 0; j < 4; ++j)
        bfr[j] = *(const bf16x8*)&lB[(wc * 64 + j * 16 + (lane & 15)) * 64 + kof];
#pragma unroll
      for (int i = 0; i < 4; ++i)
#pragma unroll
        for (int j = 0; j < 4; ++j)
          acc[i][j] = __builtin_amdgcn_mfma_f32_16x16x32_bf16(af[i], bfr[j], acc[i][j], 0, 0, 0);
    }
    __syncthreads();
  }

  const int crow0 = (lane >> 4) * 4;
  const int ccol = lane & 15;
#pragma unroll
  for (int i = 0; i < 4; ++i) {
#pragma unroll
    for (int j = 0; j < 4; ++j) {
      int col = n0 + wc * 64 + j * 16 + ccol;
      if (col >= N) continue;
#pragma unroll
      for (int v = 0; v < 4; ++v) {
        int row = m0 + wr * 64 + i * 16 + crow0 + v;
        float val = acc[i][j][v];
        if (EPI == EPI_SOFTPLUS) {
          val += bias[col];
          val = (val > 20.f) ? val : log1pf(expf(val));
        } else if (EPI == EPI_RESID) {
          val += resid[(size_t)row * ldc + col];
        }
        C[(size_t)row * ldc + col] = val;
      }
    }
  }
}

// ---------------- causal depthwise conv K=4 + SiLU ----------------
__global__ __launch_bounds__(256) void conv_silu_kernel(const float* __restrict__ xz,
                                                        const float* __restrict__ cw,
                                                        const float* __restrict__ cb,
                                                        float* __restrict__ xcf,
                                                        bf16* __restrict__ xcb) {
  int idx = blockIdx.x * 256 + threadIdx.x;  // over B*L*DIN
  int d = idx & (DIN - 1);
  int bl = idx >> 11;
  int l = bl & (LSEQ - 1);
  float acc = cb[d];
  const float* base = xz + (size_t)bl * 4096 + d;
#pragma unroll
  for (int k = 0; k < 4; ++k) {
    int ll = l - 3 + k;
    if (ll >= 0) acc += base[(ptrdiff_t)(k - 3) * 4096] * cw[d * 4 + k];
  }
  float sv = silu_f(acc);
  xcf[idx] = sv;
  xcb[idx] = (bf16)sv;
}

// ---------------- extract dt_x cols [0,128) -> bf16 ----------------
__global__ __launch_bounds__(256) void extract_dtx_kernel(const float* __restrict__ xdbl,
                                                          bf16* __restrict__ dtx) {
  int i = blockIdx.x * 256 + threadIdx.x;  // 4096*128
  int r = i >> 7, c = i & 127;
  dtx[i] = (bf16)xdbl[(size_t)r * 160 + c];
}

// ================= chunked parallel selective scan =================
// P1: per (b, chunk, d) thread: chunk transition (P = prod dA, Q = h from 0).
// P2: per (b,d,n) thread: sequential combine over 64 chunks; writes h_in
//     (state BEFORE chunk c) in-place over Q.
// P3: per (b, chunk, d) thread: replay chunk from h_in, fuse y + D*x and
//     silu(z) gate, store bf16.

__global__ __launch_bounds__(256) void scan_p1(const float* __restrict__ dt,
                                               const float* __restrict__ xc,
                                               const float* __restrict__ xdbl,
                                               const float* __restrict__ A_log,
                                               float* __restrict__ sumP,
                                               float* __restrict__ sumQ) {
  const int idx = blockIdx.x;         // [b][c][dtile]
  const int dtile = idx & 7;
  const int c = (idx >> 3) & (NC - 1);
  const int b = idx >> 9;
  const int t = threadIdx.x;
  const int d = dtile * 256 + t;

  __shared__ float bc[LC * 32];       // per-l: B[0:16], C[16:32]
  for (int i = t; i < LC * 32; i += 256) {
    int ll = i >> 5, j = i & 31;
    bc[i] = xdbl[(size_t)(b * LSEQ + c * LC + ll) * 160 + 128 + j];
  }
  __syncthreads();

  float Acoef[16];
  {
    const f32x4* Ap = (const f32x4*)(A_log + (size_t)d * 16);
#pragma unroll
    for (int q = 0; q < 4; ++q) {
      f32x4 av = Ap[q];
      Acoef[q * 4 + 0] = -__expf(av.x);
      Acoef[q * 4 + 1] = -__expf(av.y);
      Acoef[q * 4 + 2] = -__expf(av.z);
      Acoef[q * 4 + 3] = -__expf(av.w);
    }
  }

  float h[16], P[16];
#pragma unroll
  for (int n = 0; n < 16; ++n) { h[n] = 0.f; P[n] = 1.f; }

  const float* dtp = dt + ((size_t)(b * LSEQ + c * LC)) * DIN + d;
  const float* xp  = xc + ((size_t)(b * LSEQ + c * LC)) * DIN + d;
#pragma unroll 4
  for (int l = 0; l < LC; ++l) {
    float dtv = dtp[(size_t)l * DIN];
    float xv  = xp[(size_t)l * DIN];
    float du = dtv * xv;
    const float* Bl = &bc[l * 32];
#pragma unroll
    for (int n = 0; n < 16; ++n) {
      float dA = __expf(dtv * Acoef[n]);
      h[n] = dA * h[n] + du * Bl[n];
      P[n] *= dA;
    }
  }

  f32x4* op = (f32x4*)(sumP + ((size_t)(b * NC + c) * DIN + d) * 16);
  f32x4* oq = (f32x4*)(sumQ + ((size_t)(b * NC + c) * DIN + d) * 16);
#pragma unroll
  for (int q = 0; q < 4; ++q) {
    f32x4 pv, qv;
    pv.x = P[q*4+0]; pv.y = P[q*4+1]; pv.z = P[q*4+2]; pv.w = P[q*4+3];
    qv.x = h[q*4+0]; qv.y = h[q*4+1]; qv.z = h[q*4+2]; qv.w = h[q*4+3];
    op[q] = pv; oq[q] = qv;
  }
}

__global__ __launch_bounds__(256) void scan_p2(const float* __restrict__ sumP,
                                               float* __restrict__ sumQ) {
  int tid = blockIdx.x * 256 + threadIdx.x;   // b*32768 + d*16 + n
  int b = tid >> 15;
  int dn = tid & 32767;
  size_t base = (size_t)b * NC * DIN * 16 + dn;
  float h = 0.f;
#pragma unroll 4
  for (int c = 0; c < NC; ++c) {
    size_t o = base + (size_t)c * (DIN * 16);
    float Pv = sumP[o];
    float Qv = sumQ[o];
    sumQ[o] = h;            // h_in for chunk c
    h = Pv * h + Qv;
  }
}

__global__ __launch_bounds__(256) void scan_p3(const float* __restrict__ dt,
                                               const float* __restrict__ xc,
                                               const float* __restrict__ xdbl,
                                               const float* __restrict__ A_log,
                                               const float* __restrict__ hin,
                                               const float* __restrict__ xz,
                                               const float* __restrict__ Dp,
                                               bf16* __restrict__ y) {
  const int idx = blockIdx.x;
  const int dtile = idx & 7;
  const int c = (idx >> 3) & (NC - 1);
  const int b = idx >> 9;
  const int t = threadIdx.x;
  const int d = dtile * 256 + t;

  __shared__ float bc[LC * 32];
  for (int i = t; i < LC * 32; i += 256) {
    int ll = i >> 5, j = i & 31;
    bc[i] = xdbl[(size_t)(b * LSEQ + c * LC + ll) * 160 + 128 + j];
  }
  __syncthreads();

  float Acoef[16];
  {
    const f32x4* Ap = (const f32x4*)(A_log + (size_t)d * 16);
#pragma unroll
    for (int q = 0; q < 4; ++q) {
      f32x4 av = Ap[q];
      Acoef[q * 4 + 0] = -__expf(av.x);
      Acoef[q * 4 + 1] = -__expf(av.y);
      Acoef[q * 4 + 2] = -__expf(av.z);
      Acoef[q * 4 + 3] = -__expf(av.w);
    }
  }

  float h[16];
  {
    const f32x4* hp = (const f32x4*)(hin + ((size_t)(b * NC + c) * DIN + d) * 16);
#pragma unroll
    for (int q = 0; q < 4; ++q) {
      f32x4 hv = hp[q];
      h[q*4+0] = hv.x; h[q*4+1] = hv.y; h[q*4+2] = hv.z; h[q*4+3] = hv.w;
    }
  }
  float Dv = Dp[d];

  const float* dtp = dt + ((size_t)(b * LSEQ + c * LC)) * DIN + d;
  const float* xp  = xc + ((size_t)(b * LSEQ + c * LC)) * DIN + d;
  const float* zp  = xz + ((size_t)(b * LSEQ + c * LC)) * 4096 + DIN + d;
  bf16* yp = y + ((size_t)(b * LSEQ + c * LC)) * DIN + d;

#pragma unroll 4
  for (int l = 0; l < LC; ++l) {
    float dtv = dtp[(size_t)l * DIN];
    float xv  = xp[(size_t)l * DIN];
    float du = dtv * xv;
    const float* Bl = &bc[l * 32];
    float yv = 0.f;
#pragma unroll
    for (int n = 0; n < 16; ++n) {
      float dA = __expf(dtv * Acoef[n]);
      h[n] = dA * h[n] + du * Bl[n];
      yv += h[n] * Bl[16 + n];
    }
    float zv = zp[(size_t)l * 4096];
    float outv = (yv + Dv * xv) * silu_f(zv);
    yp[(size_t)l * DIN] = (bf16)outv;
  }
}

// ---------------- launch ----------------
extern "C" void kernel_launch(void* const* d_in, const int* in_sizes, int n_in,
                              void* d_out, int out_size, void* d_ws, size_t ws_size,
                              hipStream_t stream) {
  const float* x = (const float*)d_in[0];
  const float* norm_w = (const float*)d_in[1];
  const float* in_proj_w = (const float*)d_in[2];
  const float* conv_w = (const float*)d_in[3];
  const float* conv_b = (const float*)d_in[4];
  const float* x_proj_w = (const float*)d_in[5];
  const float* dt_proj_w = (const float*)d_in[6];
  const float* dt_proj_b = (const float*)d_in[7];
  const float* A_log = (const float*)d_in[8];
  const float* D_param = (const float*)d_in[9];
  const float* out_proj_w = (const float*)d_in[10];
  float* out = (float*)d_out;

  size_t off = 0;
  char* wsb = (char*)d_ws;
  auto alloc = [&](size_t bytes) {
    void* p = wsb + off;
    off += (bytes + 255) & ~(size_t)255;
    return p;
  };
  bf16* xn = (bf16*)alloc((size_t)BLROWS * HD * 2);
  bf16* w_in = (bf16*)alloc((size_t)4096 * HD * 2);
  float* xz = (float*)alloc((size_t)BLROWS * 4096 * 4);
  float* xcf = (float*)alloc((size_t)BLROWS * DIN * 4);
  bf16* xcb = (bf16*)alloc((size_t)BLROWS * DIN * 2);
  bf16* xpw = (bf16*)alloc((size_t)256 * DIN * 2);
  float* xdbl = (float*)alloc((size_t)BLROWS * 160 * 4);
  bf16* dtx = (bf16*)alloc((size_t)BLROWS * RNK * 2);
  bf16* dtw = (bf16*)alloc((size_t)DIN * RNK * 2);
  float* dtf = (float*)alloc((size_t)BLROWS * DIN * 4);
  bf16* yb = (bf16*)alloc((size_t)BLROWS * DIN * 2);
  bf16* outw = (bf16*)alloc((size_t)HD * DIN * 2);
  float* sumP = (float*)alloc((size_t)2 * NC * DIN * NST * 4);  // 16 MB
  float* sumQ = (float*)alloc((size_t)2 * NC * DIN * NST * 4);  // 16 MB
  (void)ws_size; (void)n_in; (void)in_sizes; (void)out_size;

  // convert weights to bf16
  cvt_bf16_kernel<<<(4096 * HD / 4 + 255) / 256, 256, 0, stream>>>(in_proj_w, w_in, 4096 * HD / 4);
  cvt_bf16_kernel<<<(160 * DIN / 4 + 255) / 256, 256, 0, stream>>>(x_proj_w, xpw, 160 * DIN / 4);
  cvt_bf16_kernel<<<(DIN * RNK / 4 + 255) / 256, 256, 0, stream>>>(dt_proj_w, dtw, DIN * RNK / 4);
  cvt_bf16_kernel<<<(HD * DIN / 4 + 255) / 256, 256, 0, stream>>>(out_proj_w, outw, HD * DIN / 4);

  // rmsnorm
  rmsnorm_kernel<<<BLROWS, 256, 0, stream>>>(x, norm_w, xn);

  // xz = xn @ in_proj_w^T : M=4096 N=4096 K=1024
  gemm_bt<EPI_NONE><<<dim3(32, 32), 256, 0, stream>>>(xn, w_in, xz, nullptr, nullptr,
                                                      BLROWS, 4096, HD, 4096);

  // conv + silu
  conv_silu_kernel<<<(BLROWS * DIN) / 256, 256, 0, stream>>>(xz, conv_w, conv_b, xcf, xcb);

  // x_dbl = xc @ x_proj_w^T : M=4096 N=160 K=2048
  gemm_bt<EPI_NONE><<<dim3(2, 32), 256, 0, stream>>>(xcb, xpw, xdbl, nullptr, nullptr,
                                                     BLROWS, 160, DIN, 160);

  // dt_x -> bf16
  extract_dtx_kernel<<<(BLROWS * RNK) / 256, 256, 0, stream>>>(xdbl, dtx);

  // dt = softplus(dt_x @ dt_proj_w^T + b) : M=4096 N=2048 K=128
  gemm_bt<EPI_SOFTPLUS><<<dim3(16, 32), 256, 0, stream>>>(dtx, dtw, dtf, dt_proj_b, nullptr,
                                                          BLROWS, DIN, RNK, DIN);

  // chunked parallel selective scan
  scan_p1<<<2 * NC * 8, 256, 0, stream>>>(dtf, xcf, xdbl, A_log, sumP, sumQ);
  scan_p2<<<(2 * DIN * NST) / 256, 256, 0, stream>>>(sumP, sumQ);
  scan_p3<<<2 * NC * 8, 256, 0, stream>>>(dtf, xcf, xdbl, A_log, sumQ, xz, D_param, yb);

  // out = y @ out_proj_w^T + residual : M=4096 N=1024 K=2048
  gemm_bt<EPI_RESID><<<dim3(8, 32), 256, 0, stream>>>(yb, outw, out, nullptr, x,
                                                      BLROWS, HD, DIN, HD);
}

// Round 3
// 409.911 us; speedup vs baseline: 3.8802x; 1.0723x over previous
//
#include <hip/hip_runtime.h>
#include <hip/hip_bf16.h>
#include <math.h>

typedef __bf16 bf16;
typedef bf16 bf16x8 __attribute__((ext_vector_type(8)));
typedef float f32x4 __attribute__((ext_vector_type(4)));

#define BLROWS 4096   // B*L
#define HD 1024
#define DIN 2048
#define NST 16
#define RNK 128
#define LSEQ 2048
#define NC 64         // chunks along L
#define LC 32         // L per chunk

// ---------------- helpers ----------------
__device__ __forceinline__ void gload_lds16(const void* g, void* l) {
  __builtin_amdgcn_global_load_lds(
      (const __attribute__((address_space(1))) unsigned int*)g,
      (__attribute__((address_space(3))) unsigned int*)l, 16, 0, 0);
}

__device__ __forceinline__ float silu_f(float x) {
  return x / (1.f + __expf(-x));
}

// ---------------- merged f32 -> bf16 weight convert ----------------
// ranges (in f32x4 units): in_proj 1048576 | x_proj 81920 | dt_proj 65536 | out_proj 524288
__global__ __launch_bounds__(256) void cvt_all_kernel(const float* __restrict__ w0, bf16* __restrict__ o0,
                                                      const float* __restrict__ w1, bf16* __restrict__ o1,
                                                      const float* __restrict__ w2, bf16* __restrict__ o2,
                                                      const float* __restrict__ w3, bf16* __restrict__ o3) {
  int i = blockIdx.x * 256 + threadIdx.x;
  const float* s; bf16* d; int j;
  if (i < 1048576)      { s = w0; d = o0; j = i; }
  else if (i < 1130496) { s = w1; d = o1; j = i - 1048576; }
  else if (i < 1196032) { s = w2; d = o2; j = i - 1130496; }
  else                  { s = w3; d = o3; j = i - 1196032; }
  f32x4 v = *(const f32x4*)(s + (size_t)j * 4);
  bf16* o = d + (size_t)j * 4;
  o[0] = (bf16)v.x; o[1] = (bf16)v.y; o[2] = (bf16)v.z; o[3] = (bf16)v.w;
}

// ---------------- RMSNorm -> bf16 ----------------
__global__ __launch_bounds__(256) void rmsnorm_kernel(const float* __restrict__ x,
                                                      const float* __restrict__ w,
                                                      bf16* __restrict__ xn) {
  int row = blockIdx.x;
  int t = threadIdx.x;
  const float* xr = x + (size_t)row * HD;
  f32x4 v = *(const f32x4*)(xr + t * 4);
  float s = v.x * v.x + v.y * v.y + v.z * v.z + v.w * v.w;
#pragma unroll
  for (int m = 1; m < 64; m <<= 1) s += __shfl_xor(s, m, 64);
  __shared__ float red[4];
  if ((t & 63) == 0) red[t >> 6] = s;
  __syncthreads();
  float tot = red[0] + red[1] + red[2] + red[3];
  float sc = rsqrtf(tot * (1.f / HD) + 1e-6f);
  const float* wr = w + t * 4;
  bf16* o = xn + (size_t)row * HD + t * 4;
  o[0] = (bf16)(v.x * sc * wr[0]);
  o[1] = (bf16)(v.y * sc * wr[1]);
  o[2] = (bf16)(v.z * sc * wr[2]);
  o[3] = (bf16)(v.w * sc * wr[3]);
}

// ---------------- GEMM: C[M,N] = A[M,K] * B[N,K]^T (+ epilogue) ----------------
// BM=BN=128, BK=64, 256 threads (4 waves 2x2). Optional split-K via blockIdx.z.
enum { EPI_NONE = 0, EPI_SOFTPLUS = 1 };

template <int EPI, typename CT>
__global__ __launch_bounds__(256, 2) void gemm_bt(const bf16* __restrict__ A,
                                                  const bf16* __restrict__ B,
                                                  CT* __restrict__ C,
                                                  const float* __restrict__ bias,
                                                  int M, int N, int ldab, int Kslice,
                                                  int ldc, long long strideC) {
  __shared__ __align__(16) bf16 lA[128 * 64];
  __shared__ __align__(16) bf16 lB[128 * 64];
  const int tid = threadIdx.x;
  const int wave = tid >> 6;
  const int lane = tid & 63;
  const int m0 = blockIdx.y * 128;
  const int n0 = blockIdx.x * 128;
  const int kz = blockIdx.z;
  const bf16* Ab = A + (size_t)kz * Kslice;
  const bf16* Bb = B + (size_t)kz * Kslice;
  CT* Cb = C + (size_t)kz * strideC;
  const int wr = wave >> 1, wc = wave & 1;
  f32x4 acc[4][4] = {};
  const int lrow = lane >> 3;
  const int lcole = (lane & 7) * 8;

  for (int k0 = 0; k0 < Kslice; k0 += 64) {
#pragma unroll
    for (int j = 0; j < 4; ++j) {
      int chunk = wave * 4 + j;
      int row = chunk * 8 + lrow;
      gload_lds16(Ab + (size_t)(m0 + row) * ldab + k0 + lcole, lA + chunk * 512);
      gload_lds16(Bb + (size_t)(n0 + row) * ldab + k0 + lcole, lB + chunk * 512);
    }
    __syncthreads();
#pragma unroll
    for (int kk = 0; kk < 64; kk += 32) {
      bf16x8 af[4], bfr[4];
      const int kof = kk + ((lane >> 4) * 8);
#pragma unroll
      for (int i = 0; i < 4; ++i)
        af[i] = *(const bf16x8*)&lA[(wr * 64 + i * 16 + (lane & 15)) * 64 + kof];
#pragma unroll
      for (int j = 0; j < 4; ++j)
        bfr[j] = *(const bf16x8*)&lB[(wc * 64 + j * 16 + (lane & 15)) * 64 + kof];
#pragma unroll
      for (int i = 0; i < 4; ++i)
#pragma unroll
        for (int j = 0; j < 4; ++j)
          acc[i][j] = __builtin_amdgcn_mfma_f32_16x16x32_bf16(af[i], bfr[j], acc[i][j], 0, 0, 0);
    }
    __syncthreads();
  }

  const int crow0 = (lane >> 4) * 4;
  const int ccol = lane & 15;
#pragma unroll
  for (int i = 0; i < 4; ++i) {
#pragma unroll
    for (int j = 0; j < 4; ++j) {
      int col = n0 + wc * 64 + j * 16 + ccol;
      if (col >= N) continue;
#pragma unroll
      for (int v = 0; v < 4; ++v) {
        int row = m0 + wr * 64 + i * 16 + crow0 + v;
        float val = acc[i][j][v];
        if (EPI == EPI_SOFTPLUS) {
          val += bias[col];
          val = (val > 20.f) ? val : log1pf(expf(val));
        }
        Cb[(size_t)row * ldc + col] = (CT)val;
      }
    }
  }
}

// ---------------- GEMM4: BM=128, BN=64, resid epilogue, f32 out ----------------
__global__ __launch_bounds__(256, 2) void gemm_resid64(const bf16* __restrict__ A,
                                                       const bf16* __restrict__ B,
                                                       float* __restrict__ C,
                                                       const float* __restrict__ resid,
                                                       int K, int ldc) {
  __shared__ __align__(16) bf16 lA[128 * 64];
  __shared__ __align__(16) bf16 lB[64 * 64];
  const int tid = threadIdx.x;
  const int wave = tid >> 6;
  const int lane = tid & 63;
  const int m0 = blockIdx.y * 128;
  const int n0 = blockIdx.x * 64;
  const int wr = wave >> 1, wc = wave & 1;
  f32x4 acc[4][2] = {};
  const int lrow = lane >> 3;
  const int lcole = (lane & 7) * 8;

  for (int k0 = 0; k0 < K; k0 += 64) {
#pragma unroll
    for (int j = 0; j < 4; ++j) {
      int chunk = wave * 4 + j;
      int row = chunk * 8 + lrow;
      gload_lds16(A + (size_t)(m0 + row) * K + k0 + lcole, lA + chunk * 512);
    }
#pragma unroll
    for (int j = 0; j < 2; ++j) {
      int chunk = wave * 2 + j;
      int row = chunk * 8 + lrow;
      gload_lds16(B + (size_t)(n0 + row) * K + k0 + lcole, lB + chunk * 512);
    }
    __syncthreads();
#pragma unroll
    for (int kk = 0; kk < 64; kk += 32) {
      bf16x8 af[4], bfr[2];
      const int kof = kk + ((lane >> 4) * 8);
#pragma unroll
      for (int i = 0; i < 4; ++i)
        af[i] = *(const bf16x8*)&lA[(wr * 64 + i * 16 + (lane & 15)) * 64 + kof];
#pragma unroll
      for (int j = 0; j < 2; ++j)
        bfr[j] = *(const bf16x8*)&lB[(wc * 32 + j * 16 + (lane & 15)) * 64 + kof];
#pragma unroll
      for (int i = 0; i < 4; ++i)
#pragma unroll
        for (int j = 0; j < 2; ++j)
          acc[i][j] = __builtin_amdgcn_mfma_f32_16x16x32_bf16(af[i], bfr[j], acc[i][j], 0, 0, 0);
    }
    __syncthreads();
  }

  const int crow0 = (lane >> 4) * 4;
  const int ccol = lane & 15;
#pragma unroll
  for (int i = 0; i < 4; ++i) {
#pragma unroll
    for (int j = 0; j < 2; ++j) {
      int col = n0 + wc * 32 + j * 16 + ccol;
#pragma unroll
      for (int v = 0; v < 4; ++v) {
        int row = m0 + wr * 64 + i * 16 + crow0 + v;
        C[(size_t)row * ldc + col] = acc[i][j][v] + resid[(size_t)row * ldc + col];
      }
    }
  }
}

// ---------------- causal depthwise conv K=4 + SiLU (bf16 in/out, 8-wide) ----------------
__global__ __launch_bounds__(256) void conv_silu_kernel(const bf16* __restrict__ xz,
                                                        const float* __restrict__ cw,
                                                        const float* __restrict__ cb,
                                                        bf16* __restrict__ xcb) {
  int i8 = blockIdx.x * 256 + threadIdx.x;   // over B*L*(DIN/8) = 1048576
  int d8 = i8 & 255;
  int bl = i8 >> 8;
  int l = bl & (LSEQ - 1);
  const bf16* base = xz + (size_t)bl * 4096 + d8 * 8;
  float acc[8];
  {
    const f32x4* cbp = (const f32x4*)(cb + d8 * 8);
    f32x4 c0 = cbp[0], c1 = cbp[1];
    acc[0] = c0.x; acc[1] = c0.y; acc[2] = c0.z; acc[3] = c0.w;
    acc[4] = c1.x; acc[5] = c1.y; acc[6] = c1.z; acc[7] = c1.w;
  }
  const f32x4* cwp = (const f32x4*)(cw + (size_t)d8 * 32);  // [8 d][4 taps]
#pragma unroll
  for (int k = 0; k < 4; ++k) {
    int ll = l - 3 + k;
    if (ll < 0) continue;
    bf16x8 v = *(const bf16x8*)(base + (ptrdiff_t)(k - 3) * 4096);
#pragma unroll
    for (int dd = 0; dd < 8; ++dd) acc[dd] += (float)v[dd] * cwp[dd][k];
  }
  bf16x8 o;
#pragma unroll
  for (int dd = 0; dd < 8; ++dd) o[dd] = (bf16)silu_f(acc[dd]);
  *(bf16x8*)(xcb + (size_t)bl * DIN + d8 * 8) = o;
}

// ---------------- split-K reduce for x_dbl: -> dtx(bf16) + bc(f32) ----------------
__global__ __launch_bounds__(256) void reduce_xdbl_kernel(const float* __restrict__ part,
                                                          bf16* __restrict__ dtx,
                                                          float* __restrict__ bcb) {
  int r = blockIdx.x;       // 4096 rows
  int t = threadIdx.x;
  if (t >= 160) return;
  size_t o = (size_t)r * 160 + t;
  float s = part[o] + part[o + 655360] + part[o + 2 * 655360] + part[o + 3 * 655360];
  if (t < 128) dtx[(size_t)r * 128 + t] = (bf16)s;
  else bcb[(size_t)r * 32 + (t - 128)] = s;
}

// ================= chunked parallel selective scan =================
__global__ __launch_bounds__(256) void scan_p1(const float* __restrict__ dt,
                                               const bf16* __restrict__ xc,
                                               const float* __restrict__ bcb,
                                               const float* __restrict__ A_log,
                                               float* __restrict__ sumP,
                                               float* __restrict__ sumQ) {
  const int idx = blockIdx.x;         // [b][c][dtile]
  const int dtile = idx & 7;
  const int c = (idx >> 3) & (NC - 1);
  const int b = idx >> 9;
  const int t = threadIdx.x;
  const int d = dtile * 256 + t;
  const size_t rowbase = (size_t)(b * LSEQ + c * LC);

  __shared__ __align__(16) float s_dt[LC * 256];
  __shared__ __align__(16) bf16 s_x[LC * 256];
  __shared__ __align__(16) float s_bc[LC * 32];
  {
    const f32x4* gdt = (const f32x4*)(dt + rowbase * DIN + dtile * 256);
    f32x4* sdt = (f32x4*)s_dt;
#pragma unroll
    for (int i = 0; i < 8; ++i) {
      int v = t + 256 * i, r = v >> 6, q = v & 63;
      sdt[v] = gdt[(size_t)r * (DIN / 4) + q];
    }
    const bf16x8* gx = (const bf16x8*)(xc + rowbase * DIN + dtile * 256);
    bf16x8* sx = (bf16x8*)s_x;
#pragma unroll
    for (int i = 0; i < 4; ++i) {
      int u = t + 256 * i, r = u >> 5, q = u & 31;
      sx[u] = gx[(size_t)r * (DIN / 8) + q];
    }
    ((f32x4*)s_bc)[t] = ((const f32x4*)(bcb + rowbase * 32))[t];
  }
  __syncthreads();

  float Acoef[16];
  {
    const f32x4* Ap = (const f32x4*)(A_log + (size_t)d * 16);
#pragma unroll
    for (int q = 0; q < 4; ++q) {
      f32x4 av = Ap[q];
      Acoef[q * 4 + 0] = -__expf(av.x);
      Acoef[q * 4 + 1] = -__expf(av.y);
      Acoef[q * 4 + 2] = -__expf(av.z);
      Acoef[q * 4 + 3] = -__expf(av.w);
    }
  }

  float h[16], P[16];
#pragma unroll
  for (int n = 0; n < 16; ++n) { h[n] = 0.f; P[n] = 1.f; }

#pragma unroll 4
  for (int l = 0; l < LC; ++l) {
    float dtv = s_dt[l * 256 + t];
    float xv = (float)s_x[l * 256 + t];
    float du = dtv * xv;
    const float* Bl = &s_bc[l * 32];
#pragma unroll
    for (int n = 0; n < 16; ++n) {
      float dA = __expf(dtv * Acoef[n]);
      h[n] = dA * h[n] + du * Bl[n];
      P[n] *= dA;
    }
  }

  f32x4* op = (f32x4*)(sumP + ((size_t)(b * NC + c) * DIN + d) * 16);
  f32x4* oq = (f32x4*)(sumQ + ((size_t)(b * NC + c) * DIN + d) * 16);
#pragma unroll
  for (int q = 0; q < 4; ++q) {
    f32x4 pv, qv;
    pv.x = P[q * 4 + 0]; pv.y = P[q * 4 + 1]; pv.z = P[q * 4 + 2]; pv.w = P[q * 4 + 3];
    qv.x = h[q * 4 + 0]; qv.y = h[q * 4 + 1]; qv.z = h[q * 4 + 2]; qv.w = h[q * 4 + 3];
    op[q] = pv; oq[q] = qv;
  }
}

__global__ __launch_bounds__(256) void scan_p2(const float* __restrict__ sumP,
                                               float* __restrict__ sumQ) {
  int tid = blockIdx.x * 256 + threadIdx.x;   // b*32768 + d*16 + n
  int b = tid >> 15;
  int dn = tid & 32767;
  size_t o = (size_t)b * NC * DIN * 16 + dn;
  float h = 0.f;
  float Pv = sumP[o], Qv = sumQ[o];
  for (int c = 0; c < NC; ++c) {
    size_t on = o + DIN * 16;
    float Pn = 0.f, Qn = 0.f;
    if (c < NC - 1) { Pn = sumP[on]; Qn = sumQ[on]; }
    sumQ[o] = h;
    h = fmaf(Pv, h, Qv);
    Pv = Pn; Qv = Qn; o = on;
  }
}

__global__ __launch_bounds__(256) void scan_p3(const float* __restrict__ dt,
                                               const bf16* __restrict__ xc,
                                               const float* __restrict__ bcb,
                                               const float* __restrict__ A_log,
                                               const float* __restrict__ hin,
                                               const bf16* __restrict__ xz,
                                               const float* __restrict__ Dp,
                                               bf16* __restrict__ y) {
  const int idx = blockIdx.x;
  const int dtile = idx & 7;
  const int c = (idx >> 3) & (NC - 1);
  const int b = idx >> 9;
  const int t = threadIdx.x;
  const int d = dtile * 256 + t;
  const size_t rowbase = (size_t)(b * LSEQ + c * LC);

  __shared__ __align__(16) float s_dt[LC * 256];
  __shared__ __align__(16) bf16 s_x[LC * 256];
  __shared__ __align__(16) bf16 s_z[LC * 256];
  __shared__ __align__(16) float s_bc[LC * 32];
  {
    const f32x4* gdt = (const f32x4*)(dt + rowbase * DIN + dtile * 256);
    f32x4* sdt = (f32x4*)s_dt;
#pragma unroll
    for (int i = 0; i < 8; ++i) {
      int v = t + 256 * i, r = v >> 6, q = v & 63;
      sdt[v] = gdt[(size_t)r * (DIN / 4) + q];
    }
    const bf16x8* gx = (const bf16x8*)(xc + rowbase * DIN + dtile * 256);
    const bf16x8* gz = (const bf16x8*)(xz + rowbase * 4096 + DIN + dtile * 256);
    bf16x8* sx = (bf16x8*)s_x;
    bf16x8* sz = (bf16x8*)s_z;
#pragma unroll
    for (int i = 0; i < 4; ++i) {
      int u = t + 256 * i, r = u >> 5, q = u & 31;
      sx[u] = gx[(size_t)r * (DIN / 8) + q];
      sz[u] = gz[(size_t)r * (4096 / 8) + q];
    }
    ((f32x4*)s_bc)[t] = ((const f32x4*)(bcb + rowbase * 32))[t];
  }
  __syncthreads();

  float Acoef[16];
  {
    const f32x4* Ap = (const f32x4*)(A_log + (size_t)d * 16);
#pragma unroll
    for (int q = 0; q < 4; ++q) {
      f32x4 av = Ap[q];
      Acoef[q * 4 + 0] = -__expf(av.x);
      Acoef[q * 4 + 1] = -__expf(av.y);
      Acoef[q * 4 + 2] = -__expf(av.z);
      Acoef[q * 4 + 3] = -__expf(av.w);
    }
  }

  float h[16];
  {
    const f32x4* hp = (const f32x4*)(hin + ((size_t)(b * NC + c) * DIN + d) * 16);
#pragma unroll
    for (int q = 0; q < 4; ++q) {
      f32x4 hv = hp[q];
      h[q * 4 + 0] = hv.x; h[q * 4 + 1] = hv.y; h[q * 4 + 2] = hv.z; h[q * 4 + 3] = hv.w;
    }
  }
  float Dv = Dp[d];

#pragma unroll 4
  for (int l = 0; l < LC; ++l) {
    float dtv = s_dt[l * 256 + t];
    float xv = (float)s_x[l * 256 + t];
    float du = dtv * xv;
    const float* Bl = &s_bc[l * 32];
    float yv = 0.f;
#pragma unroll
    for (int n = 0; n < 16; ++n) {
      float dA = __expf(dtv * Acoef[n]);
      h[n] = dA * h[n] + du * Bl[n];
      yv += h[n] * Bl[16 + n];
    }
    float zv = (float)s_z[l * 256 + t];
    float outv = (yv + Dv * xv) * silu_f(zv);
    s_x[l * 256 + t] = (bf16)outv;   // reuse s_x as y staging
  }
  __syncthreads();
  {
    bf16x8* gy = (bf16x8*)(y + rowbase * DIN + dtile * 256);
    const bf16x8* sx = (const bf16x8*)s_x;
#pragma unroll
    for (int i = 0; i < 4; ++i) {
      int u = t + 256 * i, r = u >> 5, q = u & 31;
      gy[(size_t)r * (DIN / 8) + q] = sx[u];
    }
  }
}

// ---------------- launch ----------------
extern "C" void kernel_launch(void* const* d_in, const int* in_sizes, int n_in,
                              void* d_out, int out_size, void* d_ws, size_t ws_size,
                              hipStream_t stream) {
  const float* x = (const float*)d_in[0];
  const float* norm_w = (const float*)d_in[1];
  const float* in_proj_w = (const float*)d_in[2];
  const float* conv_w = (const float*)d_in[3];
  const float* conv_b = (const float*)d_in[4];
  const float* x_proj_w = (const float*)d_in[5];
  const float* dt_proj_w = (const float*)d_in[6];
  const float* dt_proj_b = (const float*)d_in[7];
  const float* A_log = (const float*)d_in[8];
  const float* D_param = (const float*)d_in[9];
  const float* out_proj_w = (const float*)d_in[10];
  float* out = (float*)d_out;

  size_t off = 0;
  char* wsb = (char*)d_ws;
  auto alloc = [&](size_t bytes) {
    void* p = wsb + off;
    off += (bytes + 255) & ~(size_t)255;
    return p;
  };
  bf16* xn = (bf16*)alloc((size_t)BLROWS * HD * 2);
  bf16* w_in = (bf16*)alloc((size_t)4096 * HD * 2);
  bf16* xzb = (bf16*)alloc((size_t)BLROWS * 4096 * 2);   // 32 MB
  bf16* xcb = (bf16*)alloc((size_t)BLROWS * DIN * 2);
  bf16* xpw = (bf16*)alloc((size_t)256 * DIN * 2);       // padded 160->256 rows
  float* part2 = (float*)alloc((size_t)4 * BLROWS * 160 * 4);  // 10.5 MB
  bf16* dtx = (bf16*)alloc((size_t)BLROWS * RNK * 2);
  float* bcb = (float*)alloc((size_t)BLROWS * 32 * 4);
  bf16* dtw = (bf16*)alloc((size_t)DIN * RNK * 2);
  float* dtf = (float*)alloc((size_t)BLROWS * DIN * 4);
  bf16* yb = (bf16*)alloc((size_t)BLROWS * DIN * 2);
  bf16* outw = (bf16*)alloc((size_t)HD * DIN * 2);
  float* sumP = (float*)alloc((size_t)2 * NC * DIN * NST * 4);
  float* sumQ = (float*)alloc((size_t)2 * NC * DIN * NST * 4);
  (void)ws_size; (void)n_in; (void)in_sizes; (void)out_size;

  // weights -> bf16 (merged)
  cvt_all_kernel<<<6720, 256, 0, stream>>>(in_proj_w, w_in, x_proj_w, xpw,
                                           dt_proj_w, dtw, out_proj_w, outw);

  // rmsnorm
  rmsnorm_kernel<<<BLROWS, 256, 0, stream>>>(x, norm_w, xn);

  // xz = xn @ in_proj_w^T : M=4096 N=4096 K=1024 -> bf16
  gemm_bt<EPI_NONE, bf16><<<dim3(32, 32, 1), 256, 0, stream>>>(
      xn, w_in, xzb, nullptr, BLROWS, 4096, HD, HD, 4096, 0);

  // conv + silu (bf16 in/out)
  conv_silu_kernel<<<4096, 256, 0, stream>>>(xzb, conv_w, conv_b, xcb);

  // x_dbl = xc @ x_proj_w^T : M=4096 N=160 K=2048, split-K=4
  gemm_bt<EPI_NONE, float><<<dim3(2, 32, 4), 256, 0, stream>>>(
      xcb, xpw, part2, nullptr, BLROWS, 160, DIN, 512, 160, (long long)BLROWS * 160);

  // reduce partials -> dtx (bf16) + bc (f32 compact)
  reduce_xdbl_kernel<<<BLROWS, 256, 0, stream>>>(part2, dtx, bcb);

  // dt = softplus(dt_x @ dt_proj_w^T + b) : M=4096 N=2048 K=128
  gemm_bt<EPI_SOFTPLUS, float><<<dim3(16, 32, 1), 256, 0, stream>>>(
      dtx, dtw, dtf, dt_proj_b, BLROWS, DIN, RNK, RNK, DIN, 0);

  // chunked parallel selective scan
  scan_p1<<<2 * NC * 8, 256, 0, stream>>>(dtf, xcb, bcb, A_log, sumP, sumQ);
  scan_p2<<<(2 * DIN * NST) / 256, 256, 0, stream>>>(sumP, sumQ);
  scan_p3<<<2 * NC * 8, 256, 0, stream>>>(dtf, xcb, bcb, A_log, sumQ, xzb, D_param, yb);

  // out = y @ out_proj_w^T + residual : M=4096 N=1024 K=2048 (BN=64, 512 blocks)
  gemm_resid64<<<dim3(16, 32), 256, 0, stream>>>(yb, outw, out, x, DIN, HD);
}